// Round 6
// baseline (193.370 us; speedup 1.0000x reference)
//
#include <hip/hip_runtime.h>

typedef __attribute__((ext_vector_type(8))) short short8;
typedef __attribute__((ext_vector_type(4))) short short4v;
typedef __attribute__((ext_vector_type(4))) float f32x4;
typedef __attribute__((ext_vector_type(16))) float f32x16;
typedef __attribute__((ext_vector_type(2))) unsigned uint2v;
typedef __attribute__((ext_vector_type(4))) unsigned uint4v;

#define MFMA16(a,b,c) __builtin_amdgcn_mfma_f32_16x16x32_bf16((a),(b),(c),0,0,0)
#define MFMA32(a,b,c) __builtin_amdgcn_mfma_f32_32x32x16_bf16((a),(b),(c),0,0,0)

#define BB 32
#define SS 1024
#define DD 192
#define HH 8
#define DHP 32   // padded head dim (24 -> 32); col 31 = mask-bias, col 24 of V = ones

// Q pre-scale: log2(e) / sqrt(24)  -> exp2(S) == softmax numerator
#define SCALE_Q 0.294468266742895f

// native RNE conversions (compiler emits v_cvt_*_bf16, fuses pairs to cvt_pk)
__device__ __forceinline__ short nb(float f) {
    __bf16 h = (__bf16)f;
    return __builtin_bit_cast(short, h);
}
__device__ __forceinline__ float bf2f(short s) {
    union { unsigned u; float f; } v; v.u = ((unsigned)(unsigned short)s) << 16;
    return v.f;
}
__device__ __forceinline__ unsigned pk2(float a, float b) {
    unsigned short lo = __builtin_bit_cast(unsigned short, (__bf16)a);
    unsigned short hi = __builtin_bit_cast(unsigned short, (__bf16)b);
    return (unsigned)lo | ((unsigned)hi << 16);
}

// ---------------- prep: mask normalize + weight transposes ----------------
// WqT/WkT/WvT rows within a head are PERMUTED: physical row p holds actual
// col e where p = (e>>1) | ((e&1)<<4)  (so proj pass nt, lane c -> col 2c+nt)
__global__ __launch_bounds__(256) void prep_kernel(
    const void* __restrict__ mask_raw,
    const float* __restrict__ Wq, const float* __restrict__ Wk, const float* __restrict__ Wv,
    const float* __restrict__ Wo,
    float* __restrict__ maskf,
    short* __restrict__ WqT, short* __restrict__ WkT, short* __restrict__ WvT,
    short* __restrict__ WoTh, short* __restrict__ WoTl)
{
    int idx = blockIdx.x * 256 + threadIdx.x;
    const int NMASK = BB * SS;               // 32768
    const int NWX   = 3 * HH * DHP * DD;     // 147456
    const int NWO   = DD * DD;               // 36864
    if (idx < NMASK) {
        // dtype sniff: bool may arrive as int32 (0/1), float32 (0.0/1.0) or uint8
        const unsigned* mw = (const unsigned*)mask_raw;
        bool all01 = true, allf = true;
        #pragma unroll
        for (int i = 0; i < 16; i++) {
            unsigned w = mw[i];
            all01 = all01 && (w <= 1u);
            allf  = allf  && (w == 0u || w == 0x3F800000u);
        }
        float m;
        if (all01)      m = (mw[idx] != 0u) ? 1.f : 0.f;
        else if (allf)  m = (((const float*)mask_raw)[idx] != 0.f) ? 1.f : 0.f;
        else            m = (((const unsigned char*)mask_raw)[idx] != 0) ? 1.f : 0.f;
        maskf[idx] = m;
    } else if (idx < NMASK + NWX) {
        int j = idx - NMASK;
        int mat = j / (HH * DHP * DD);
        int jj  = j % (HH * DHP * DD);
        int h   = jj / (DHP * DD);
        int rem = jj % (DHP * DD);
        int e   = rem / DD;       // actual output col
        int d   = rem % DD;
        const float* W = (mat == 0) ? Wq : (mat == 1) ? Wk : Wv;
        short* WT      = (mat == 0) ? WqT : (mat == 1) ? WkT : WvT;
        float val = (e < 24) ? W[(h * DD + d) * 24 + e] : 0.f;   // pad e>=24 with 0
        int p = (e >> 1) | ((e & 1) << 4);                       // permuted row
        WT[(h * DHP + p) * DD + d] = nb(val);
    } else if (idx < NMASK + NWX + NWO) {
        int j = idx - NMASK - NWX;
        int n = j / DD, k = j % DD;
        float f = Wo[k * DD + n];
        short hi = nb(f);
        WoTh[n * DD + k] = hi;
        WoTl[n * DD + k] = nb(f - bf2f(hi));   // split-bf16 low part
    }
}

// ---------------- proj: Q/K/V = x @ W + b via MFMA ----------------
// blockIdx.y = mat (0=Q, 1=K, 2=V) — occupancy: 1536 blocks = 6/CU
// Q is pre-scaled by SCALE_Q, Q[:,31] = 1.0 (bias channel input)
// K[:,31]   = mask ? 0 : -1e30 (bias channel: QK^T gets -1e30 on masked k)
// V[:,24]   = 1.0 (ones column: PV MFMA computes softmax denominator for free)
__global__ __launch_bounds__(256) void proj_kernel(
    const float* __restrict__ x,
    const float* __restrict__ bq, const float* __restrict__ bk, const float* __restrict__ bv,
    const short* __restrict__ WqT, const short* __restrict__ WkT, const short* __restrict__ WvT,
    const float* __restrict__ maskf,
    short* __restrict__ Q, short* __restrict__ K, short* __restrict__ Vt)
{
    int mat = blockIdx.y;
    int tid = threadIdx.x;
    int lane = tid & 63, w = tid >> 6;
    int c = lane & 15, g = lane >> 4;
    int r0 = blockIdx.x * 64 + w * 16;
    int arow = r0 + c;

    // output row block for this thread: rows s0..s0+3 (same batch: 64 | 1024)
    int b_ = r0 >> 10;
    int s0 = (r0 & 1023) + g * 4;

    const short* WT   = (mat==0)?WqT:(mat==1)?WkT:WvT;
    const float* bias = (mat==0)?bq:(mat==1)?bk:bv;

    short8 a[6];
    #pragma unroll
    for (int kk = 0; kk < 6; kk++) {
        const float* px = x + (size_t)arow * DD + kk * 32 + g * 8;
        float4 f0 = *(const float4*)px;
        float4 f1 = *(const float4*)(px + 4);
        short8 t;
        t[0]=nb(f0.x); t[1]=nb(f0.y); t[2]=nb(f0.z); t[3]=nb(f0.w);
        t[4]=nb(f1.x); t[5]=nb(f1.y); t[6]=nb(f1.z); t[7]=nb(f1.w);
        a[kk] = t;
    }

    // mask values for this thread's 4 rows (only needed by c==15 for K)
    float mrow[4];
    if (mat == 1) {
        #pragma unroll
        for (int r = 0; r < 4; r++) mrow[r] = maskf[b_ * SS + s0 + r];
    }

    for (int h = 0; h < HH; h++) {
        int bh = b_ * HH + h;

        f32x4 acc0 = {0.f,0.f,0.f,0.f};   // actual col 2c
        f32x4 acc1 = {0.f,0.f,0.f,0.f};   // actual col 2c+1
        const short* Wp0 = WT + (size_t)(h * DHP + c) * DD + g * 8;
        const short* Wp1 = WT + (size_t)(h * DHP + 16 + c) * DD + g * 8;
        #pragma unroll
        for (int kk = 0; kk < 6; kk++) {
            short8 b0 = *(const short8*)(Wp0 + kk * 32);
            short8 b1 = *(const short8*)(Wp1 + kk * 32);
            acc0 = MFMA16(a[kk], b0, acc0);
            acc1 = MFMA16(a[kk], b1, acc1);
        }
        // bias for cols 2c, 2c+1 (0 when >= 24)
        float bv0 = 0.f, bv1 = 0.f;
        if (2*c < 24) {
            float2 bb = *(const float2*)(bias + h * 24 + 2 * c);
            bv0 = bb.x; bv1 = bb.y;
        }

        if (mat == 0) {
            #pragma unroll
            for (int r = 0; r < 4; r++) {
                float v0 = (acc0[r] + bv0) * SCALE_Q;
                float v1 = (c == 15) ? 1.0f : (acc1[r] + bv1) * SCALE_Q;
                *(unsigned*)(Q + ((size_t)bh * SS + s0 + r) * DHP + 2*c) = pk2(v0, v1);
            }
        } else if (mat == 1) {
            #pragma unroll
            for (int r = 0; r < 4; r++) {
                float v0 = acc0[r] + bv0;
                float v1 = (c == 15) ? ((mrow[r] != 0.f) ? 0.f : -1e30f)
                                     : (acc1[r] + bv1);
                *(unsigned*)(K + ((size_t)bh * SS + s0 + r) * DHP + 2*c) = pk2(v0, v1);
            }
        } else {
            short4v sv0, sv1;
            #pragma unroll
            for (int r = 0; r < 4; r++) {
                // col 24 (c==12, even slot) = ones column for denominator
                sv0[r] = (c == 12) ? (short)0x3F80 : nb(acc0[r] + bv0);
                sv1[r] = nb(acc1[r] + bv1);
            }
            *(short4v*)(Vt + ((size_t)bh * DHP + 2*c) * SS + s0)     = sv0;
            *(short4v*)(Vt + ((size_t)bh * DHP + 2*c + 1) * SS + s0) = sv1;
        }
    }
}

// ---------------- flash attention (swapped QK^T, in-register softmax) ----------------
// exp2, pack to bf16, cross-half exchange via permlane32_swap, PV MFMA
__device__ __forceinline__ void fproc(const f32x16& S, f32x16& acc,
                                      short8 v0, short8 v1)
{
    float p[16];
    #pragma unroll
    for (int r = 0; r < 16; r++) p[r] = __builtin_amdgcn_exp2f(S[r]);

    // pack P pairs: lane (l31, hi) holds P[kpos = (r&3)+8*(r>>2)+4*hi][q = l31]
    unsigned c01 = pk2(p[0],  p[1]);   // kpos {0,1}+4hi
    unsigned c23 = pk2(p[2],  p[3]);   // kpos {2,3}+4hi
    unsigned c45 = pk2(p[4],  p[5]);   // kpos {8,9}+4hi
    unsigned c67 = pk2(p[6],  p[7]);   // kpos {10,11}+4hi
    unsigned c89 = pk2(p[8],  p[9]);   // kpos {16,17}+4hi
    unsigned cab = pk2(p[10], p[11]);  // kpos {18,19}+4hi
    unsigned ccd = pk2(p[12], p[13]);  // kpos {24,25}+4hi
    unsigned cef = pk2(p[14], p[15]);  // kpos {26,27}+4hi

    // permlane32_swap(a,b): x[l] = l<32 ? a[l] : b[l-32]
    //                       y[l] = l<32 ? a[l+32] : b[l]
    uint2v s0 = __builtin_amdgcn_permlane32_swap(c01, c45, false, false);
    uint2v s1 = __builtin_amdgcn_permlane32_swap(c23, c67, false, false);
    uint2v s2 = __builtin_amdgcn_permlane32_swap(c89, ccd, false, false);
    uint2v s3 = __builtin_amdgcn_permlane32_swap(cab, cef, false, false);

    uint4v w0v = { s0.x, s1.x, s0.y, s1.y };   // PV A-frag, kpos tile 0..15
    uint4v w1v = { s2.x, s3.x, s2.y, s3.y };   // kpos tile 16..31
    short8 pa0 = __builtin_bit_cast(short8, w0v);
    short8 pa1 = __builtin_bit_cast(short8, w1v);

    acc = MFMA32(pa0, v0, acc);
    acc = MFMA32(pa1, v1, acc);
}

__global__ __launch_bounds__(256) void flash_kernel(
    const short* __restrict__ Q, const short* __restrict__ K, const short* __restrict__ Vt,
    short* __restrict__ attnb)
{
    __shared__ float llds[4][2][32];

    // consecutive idx = consecutive bh (round-robin XCD); the 4 q-blocks of
    // one bh are 256 apart -> same XCD (256 % 8 == 0) -> K/V L2 locality
    int idx = blockIdx.x;
    int bh = idx & 255;
    int qb = idx >> 8;          // 0..3
    int b = bh >> 3, h = bh & 7;

    int tid = threadIdx.x;
    int lane = tid & 63, w = tid >> 6;
    int l31 = lane & 31;
    int hi = lane >> 5;

    int qrA = qb * 256 + w * 32;
    int qrB = qrA + 128;

    // Q B-fragments (col = q = l31, k-dim = head-dim e), loop-invariant
    const short* QpA = Q + ((size_t)bh * SS + qrA + l31) * DHP + hi * 8;
    const short* QpB = Q + ((size_t)bh * SS + qrB + l31) * DHP + hi * 8;
    short8 qA0 = *(const short8*)QpA;          // e = hi*8 + j
    short8 qA1 = *(const short8*)(QpA + 16);   // e = 16 + hi*8 + j
    short8 qB0 = *(const short8*)QpB;
    short8 qB1 = *(const short8*)(QpB + 16);

    const short* Kp = K + ((size_t)bh * SS + l31) * DHP + hi * 8;
    const short* Vp = Vt + ((size_t)bh * DHP + l31) * SS + hi * 8;

    f32x16 accA, accB, Z16;
    #pragma unroll
    for (int r = 0; r < 16; r++) { accA[r] = 0.f; accB[r] = 0.f; Z16[r] = 0.f; }

    for (int kt = 0; kt < 32; kt++) {
        short8 k0 = *(const short8*)(Kp);        // A: row = kpos, kdim e 0..15
        short8 k1 = *(const short8*)(Kp + 16);   //                kdim e 16..31
        short8 v0 = *(const short8*)(Vp);        // B: col = e, k = kpos 0..15
        short8 v1 = *(const short8*)(Vp + 16);   //             k = kpos 16..31
        Kp += 32 * DHP;
        Vp += 32;

        // S[kpos][q]: col = q = l31, row = kpos = (r&3) + 8*(r>>2) + 4*hi
        // D != C on MFMA: seed with loop-invariant zero tuple (no mov burst)
        f32x16 SA = MFMA32(k0, qA0, Z16);
        SA = MFMA32(k1, qA1, SA);   // includes mask bias via channel e=31
        f32x16 SB = MFMA32(k0, qB0, Z16);
        SB = MFMA32(k1, qB1, SB);

        fproc(SA, accA, v0, v1);
        fproc(SB, accB, v0, v1);
    }

    // denominator came through V's ones-column: acc col 24 (lanes l31==24)
    if (l31 == 24) {
        #pragma unroll
        for (int r = 0; r < 16; r++) {
            int row = (r & 3) + 8 * (r >> 2) + 4 * hi;
            llds[w][0][row] = __builtin_amdgcn_rcpf(accA[r]);
            llds[w][1][row] = __builtin_amdgcn_rcpf(accB[r]);
        }
    }
    __builtin_amdgcn_wave_barrier();   // same-wave LDS ordering fence

    // O: col = e = l31, row = q = (r&3) + 8*(r>>2) + 4*hi
    if (l31 < 24) {
        short* opA = attnb + ((size_t)b * SS + qrA) * DD + h * 24 + l31;
        short* opB = attnb + ((size_t)b * SS + qrB) * DD + h * 24 + l31;
        #pragma unroll
        for (int r = 0; r < 16; r++) {
            int row = (r & 3) + 8 * (r >> 2) + 4 * hi;
            opA[(size_t)row * DD] = nb(accA[r] * llds[w][0][row]);
            opB[(size_t)row * DD] = nb(accB[r] * llds[w][1][row]);
        }
    }
}

// ---------------- final: out = attn(bf16) @ Wo + bo (Wo split hi+lo) ----------------
// blockIdx.y selects half of the 12 output n-tiles — occupancy: 1024 blocks
__global__ __launch_bounds__(256) void final_kernel(
    const short* __restrict__ attnb,
    const short* __restrict__ WoTh, const short* __restrict__ WoTl,
    const float* __restrict__ bo, float* __restrict__ out)
{
    int tid = threadIdx.x;
    int lane = tid & 63, w = tid >> 6;
    int c = lane & 15, g = lane >> 4;
    int r0 = blockIdx.x * 64 + w * 16;
    int arow = r0 + c;
    int n0 = blockIdx.y * 6;

    short8 a[6];
    #pragma unroll
    for (int kk = 0; kk < 6; kk++)
        a[kk] = *(const short8*)(attnb + (size_t)arow * DD + kk * 32 + g * 8);

    f32x4 acc[6];
    #pragma unroll
    for (int n = 0; n < 6; n++) acc[n] = (f32x4){0.f,0.f,0.f,0.f};

    #pragma unroll
    for (int kk = 0; kk < 6; kk++) {
        #pragma unroll
        for (int n = 0; n < 6; n++) {
            const short* bh_p = WoTh + (size_t)((n0+n)*16 + c) * DD + kk * 32 + g * 8;
            const short* bl_p = WoTl + (size_t)((n0+n)*16 + c) * DD + kk * 32 + g * 8;
            short8 bh = *(const short8*)bh_p;
            short8 bl = *(const short8*)bl_p;
            acc[n] = MFMA16(a[kk], bh, acc[n]);
            acc[n] = MFMA16(a[kk], bl, acc[n]);
        }
    }

    #pragma unroll
    for (int n = 0; n < 6; n++) {
        int col = (n0+n)*16 + c;
        float bv = bo[col];
        #pragma unroll
        for (int r = 0; r < 4; r++) {
            out[(size_t)(r0 + g*4 + r) * DD + col] = acc[n][r] + bv;
        }
    }
}

extern "C" void kernel_launch(void* const* d_in, const int* in_sizes, int n_in,
                              void* d_out, int out_size, void* d_ws, size_t ws_size,
                              hipStream_t stream)
{
    const float* x    = (const float*)d_in[0];
    const void*  mask = d_in[1];
    const float* Wq   = (const float*)d_in[2];
    const float* bq   = (const float*)d_in[3];
    const float* Wk   = (const float*)d_in[4];
    const float* bk   = (const float*)d_in[5];
    const float* Wv   = (const float*)d_in[6];
    const float* bv   = (const float*)d_in[7];
    const float* Wo   = (const float*)d_in[8];
    const float* bo   = (const float*)d_in[9];
    float* out = (float*)d_out;

    char* ws = (char*)d_ws;
    size_t off = 0;
    float* maskf = (float*)(ws + off); off += (size_t)BB*SS*4;          // 128 KB
    short* Q     = (short*)(ws + off); off += (size_t)BB*HH*SS*DHP*2;   // 16 MB
    short* K     = (short*)(ws + off); off += (size_t)BB*HH*SS*DHP*2;   // 16 MB
    short* Vt    = (short*)(ws + off); off += (size_t)BB*HH*SS*DHP*2;   // 16 MB
    short* attnb = (short*)(ws + off); off += (size_t)BB*SS*DD*2;       // 12 MB
    short* WqT   = (short*)(ws + off); off += (size_t)HH*DHP*DD*2;
    short* WkT   = (short*)(ws + off); off += (size_t)HH*DHP*DD*2;
    short* WvT   = (short*)(ws + off); off += (size_t)HH*DHP*DD*2;
    short* WoTh  = (short*)(ws + off); off += (size_t)DD*DD*2;
    short* WoTl  = (short*)(ws + off); off += (size_t)DD*DD*2;

    prep_kernel<<<dim3(848), dim3(256), 0, stream>>>(
        mask, Wq, Wk, Wv, Wo, maskf, WqT, WkT, WvT, WoTh, WoTl);
    proj_kernel<<<dim3(512, 3), dim3(256), 0, stream>>>(
        x, bq, bk, bv, WqT, WkT, WvT, maskf, Q, K, Vt);
    flash_kernel<<<dim3(1024), dim3(256), 0, stream>>>(
        Q, K, Vt, attnb);
    final_kernel<<<dim3(512, 2), dim3(256), 0, stream>>>(
        attnb, WoTh, WoTl, bo, out);
}

// Round 7
// 122.572 us; speedup vs baseline: 1.5776x; 1.5776x over previous
//
#include <hip/hip_runtime.h>

typedef __attribute__((ext_vector_type(8))) short short8;
typedef __attribute__((ext_vector_type(4))) short short4v;
typedef __attribute__((ext_vector_type(4))) float f32x4;
typedef __attribute__((ext_vector_type(16))) float f32x16;
typedef __attribute__((ext_vector_type(2))) unsigned uint2v;
typedef __attribute__((ext_vector_type(4))) unsigned uint4v;

#define MFMA16(a,b,c) __builtin_amdgcn_mfma_f32_16x16x32_bf16((a),(b),(c),0,0,0)
#define MFMA32(a,b,c) __builtin_amdgcn_mfma_f32_32x32x16_bf16((a),(b),(c),0,0,0)

#define BB 32
#define SS 1024
#define DD 192
#define HH 8
#define DHP 32   // padded head dim (24 -> 32); col 31 = mask-bias, col 24 of V = ones

// Q pre-scale: log2(e) / sqrt(24)  -> exp2(S) == softmax numerator
#define SCALE_Q 0.294468266742895f

// native RNE conversions (compiler emits v_cvt_*_bf16, fuses pairs to cvt_pk)
__device__ __forceinline__ short nb(float f) {
    __bf16 h = (__bf16)f;
    return __builtin_bit_cast(short, h);
}
__device__ __forceinline__ float bf2f(short s) {
    union { unsigned u; float f; } v; v.u = ((unsigned)(unsigned short)s) << 16;
    return v.f;
}
__device__ __forceinline__ unsigned pk2(float a, float b) {
    unsigned short lo = __builtin_bit_cast(unsigned short, (__bf16)a);
    unsigned short hi = __builtin_bit_cast(unsigned short, (__bf16)b);
    return (unsigned)lo | ((unsigned)hi << 16);
}

// ---------------- prep: mask normalize + fragment-order weight layouts ----------------
// WqF/WkF/WvF: [(h*2+nt)*6+kk][lane=g*16+c][8] — proj B-frag loads = base + lane*16B.
//   lane (c,g) of pass nt gets W column e=2c+nt, k-elems d=kk*32+g*8+j.
// WoFh/WoFl:   [n*6+kk][lane][8] — final B-frag coalesced; n = out-col/16.
__global__ __launch_bounds__(256) void prep_kernel(
    const void* __restrict__ mask_raw,
    const float* __restrict__ Wq, const float* __restrict__ Wk, const float* __restrict__ Wv,
    const float* __restrict__ Wo,
    float* __restrict__ maskf,
    short* __restrict__ WqF, short* __restrict__ WkF, short* __restrict__ WvF,
    short* __restrict__ WoFh, short* __restrict__ WoFl)
{
    int idx = blockIdx.x * 256 + threadIdx.x;
    const int NMASK = BB * SS;               // 32768
    const int NWX   = 3 * HH * DHP * DD;     // 147456
    const int NWO   = DD * DD;               // 36864
    if (idx < NMASK) {
        // dtype sniff: bool may arrive as int32 (0/1), float32 (0.0/1.0) or uint8
        const unsigned* mw = (const unsigned*)mask_raw;
        bool all01 = true, allf = true;
        #pragma unroll
        for (int i = 0; i < 16; i++) {
            unsigned w = mw[i];
            all01 = all01 && (w <= 1u);
            allf  = allf  && (w == 0u || w == 0x3F800000u);
        }
        float m;
        if (all01)      m = (mw[idx] != 0u) ? 1.f : 0.f;
        else if (allf)  m = (((const float*)mask_raw)[idx] != 0.f) ? 1.f : 0.f;
        else            m = (((const unsigned char*)mask_raw)[idx] != 0) ? 1.f : 0.f;
        maskf[idx] = m;
    } else if (idx < NMASK + NWX) {
        int j = idx - NMASK;
        int mat = j / (HH * DHP * DD);
        int jj  = j % (HH * DHP * DD);
        int h   = jj / (DHP * DD);
        int rem = jj % (DHP * DD);
        int e   = rem / DD;       // actual output col 0..31
        int d   = rem % DD;       // input dim
        const float* W = (mat == 0) ? Wq : (mat == 1) ? Wk : Wv;
        short* WF      = (mat == 0) ? WqF : (mat == 1) ? WkF : WvF;
        float val = (e < 24) ? W[(h * DD + d) * 24 + e] : 0.f;   // pad e>=24 with 0
        int nt = e & 1, cc = e >> 1;
        int kk = d >> 5, g = (d >> 3) & 3, ee = d & 7;
        WF[(size_t)((((h*2+nt)*6 + kk)*64) + g*16 + cc)*8 + ee] = nb(val);
    } else if (idx < NMASK + NWX + NWO) {
        int j = idx - NMASK - NWX;
        int n = j / DD, k = j % DD;    // n = out col, k = in dim
        float f = Wo[k * DD + n];
        short hi = nb(f);
        int nn = n >> 4, cc = n & 15;
        int kk = k >> 5, g = (k >> 3) & 3, ee = k & 7;
        size_t addr = (size_t)(((nn*6 + kk)*64) + g*16 + cc)*8 + ee;
        WoFh[addr] = hi;
        WoFl[addr] = nb(f - bf2f(hi));   // split-bf16 low part
    }
}

// ---------------- proj: Q/K/V = x @ W + b via MFMA (coalesced weight frags) ----------------
// Q is pre-scaled by SCALE_Q, Q[:,31] = 1.0 (bias channel input)
// K[:,31]   = mask ? 0 : -1e30 (bias channel: QK^T gets -1e30 on masked k)
// V[:,24]   = 1.0 (ones column: PV MFMA computes softmax denominator for free)
__global__ __launch_bounds__(256) void proj_kernel(
    const float* __restrict__ x,
    const float* __restrict__ bq, const float* __restrict__ bk, const float* __restrict__ bv,
    const short* __restrict__ WqF, const short* __restrict__ WkF, const short* __restrict__ WvF,
    const float* __restrict__ maskf,
    short* __restrict__ Q, short* __restrict__ K, short* __restrict__ Vt)
{
    int tid = threadIdx.x;
    int lane = tid & 63, w = tid >> 6;
    int c = lane & 15, g = lane >> 4;
    int r0 = blockIdx.x * 64 + w * 16;
    int arow = r0 + c;

    // output row block for this thread: rows s0..s0+3 (same batch: 64 | 1024)
    int b_ = r0 >> 10;
    int s0 = (r0 & 1023) + g * 4;

    short8 a[6];
    #pragma unroll
    for (int kk = 0; kk < 6; kk++) {
        const float* px = x + (size_t)arow * DD + kk * 32 + g * 8;
        float4 f0 = *(const float4*)px;
        float4 f1 = *(const float4*)(px + 4);
        short8 t;
        t[0]=nb(f0.x); t[1]=nb(f0.y); t[2]=nb(f0.z); t[3]=nb(f0.w);
        t[4]=nb(f1.x); t[5]=nb(f1.y); t[6]=nb(f1.z); t[7]=nb(f1.w);
        a[kk] = t;
    }

    // mask values for this thread's 4 rows (only needed by c==15 for K)
    float mrow[4];
    #pragma unroll
    for (int r = 0; r < 4; r++) mrow[r] = maskf[b_ * SS + s0 + r];

    for (int h = 0; h < HH; h++) {
        int bh = b_ * HH + h;
        #pragma unroll
        for (int mat = 0; mat < 3; mat++) {
            const short* WF   = (mat==0)?WqF:(mat==1)?WkF:WvF;
            const float* bias = (mat==0)?bq:(mat==1)?bk:bv;

            f32x4 acc0 = {0.f,0.f,0.f,0.f};   // actual col 2c
            f32x4 acc1 = {0.f,0.f,0.f,0.f};   // actual col 2c+1
            // frag block stride per kk = 64 lanes * 8 shorts = 512
            const short* Wp0 = WF + (size_t)((h*2+0)*6) * 512 + lane * 8;
            const short* Wp1 = WF + (size_t)((h*2+1)*6) * 512 + lane * 8;
            #pragma unroll
            for (int kk = 0; kk < 6; kk++) {
                short8 b0 = *(const short8*)(Wp0 + kk * 512);
                short8 b1 = *(const short8*)(Wp1 + kk * 512);
                acc0 = MFMA16(a[kk], b0, acc0);
                acc1 = MFMA16(a[kk], b1, acc1);
            }
            // bias for cols 2c, 2c+1 (0 when >= 24)
            float bv0 = 0.f, bv1 = 0.f;
            if (2*c < 24) {
                float2 bb = *(const float2*)(bias + h * 24 + 2 * c);
                bv0 = bb.x; bv1 = bb.y;
            }

            if (mat == 0) {
                #pragma unroll
                for (int r = 0; r < 4; r++) {
                    float v0 = (acc0[r] + bv0) * SCALE_Q;
                    float v1 = (c == 15) ? 1.0f : (acc1[r] + bv1) * SCALE_Q;
                    *(unsigned*)(Q + ((size_t)bh * SS + s0 + r) * DHP + 2*c) = pk2(v0, v1);
                }
            } else if (mat == 1) {
                #pragma unroll
                for (int r = 0; r < 4; r++) {
                    float v0 = acc0[r] + bv0;
                    float v1 = (c == 15) ? ((mrow[r] != 0.f) ? 0.f : -1e30f)
                                         : (acc1[r] + bv1);
                    *(unsigned*)(K + ((size_t)bh * SS + s0 + r) * DHP + 2*c) = pk2(v0, v1);
                }
            } else {
                short4v sv0, sv1;
                #pragma unroll
                for (int r = 0; r < 4; r++) {
                    // col 24 (c==12, even slot) = ones column for denominator
                    sv0[r] = (c == 12) ? (short)0x3F80 : nb(acc0[r] + bv0);
                    sv1[r] = nb(acc1[r] + bv1);
                }
                *(short4v*)(Vt + ((size_t)bh * DHP + 2*c) * SS + s0)     = sv0;
                *(short4v*)(Vt + ((size_t)bh * DHP + 2*c + 1) * SS + s0) = sv1;
            }
        }
    }
}

// ---------------- flash attention (swapped QK^T, in-register softmax) ----------------
// exp2, pack to bf16, cross-half exchange via permlane32_swap, PV MFMA
__device__ __forceinline__ void fproc(const f32x16& S, f32x16& acc,
                                      short8 v0, short8 v1)
{
    float p[16];
    #pragma unroll
    for (int r = 0; r < 16; r++) p[r] = __builtin_amdgcn_exp2f(S[r]);

    // pack P pairs: lane (l31, hi) holds P[kpos = (r&3)+8*(r>>2)+4*hi][q = l31]
    unsigned c01 = pk2(p[0],  p[1]);   // kpos {0,1}+4hi
    unsigned c23 = pk2(p[2],  p[3]);   // kpos {2,3}+4hi
    unsigned c45 = pk2(p[4],  p[5]);   // kpos {8,9}+4hi
    unsigned c67 = pk2(p[6],  p[7]);   // kpos {10,11}+4hi
    unsigned c89 = pk2(p[8],  p[9]);   // kpos {16,17}+4hi
    unsigned cab = pk2(p[10], p[11]);  // kpos {18,19}+4hi
    unsigned ccd = pk2(p[12], p[13]);  // kpos {24,25}+4hi
    unsigned cef = pk2(p[14], p[15]);  // kpos {26,27}+4hi

    // permlane32_swap(a,b): x[l] = l<32 ? a[l] : b[l-32]
    //                       y[l] = l<32 ? a[l+32] : b[l]
    uint2v s0 = __builtin_amdgcn_permlane32_swap(c01, c45, false, false);
    uint2v s1 = __builtin_amdgcn_permlane32_swap(c23, c67, false, false);
    uint2v s2 = __builtin_amdgcn_permlane32_swap(c89, ccd, false, false);
    uint2v s3 = __builtin_amdgcn_permlane32_swap(cab, cef, false, false);

    uint4v w0v = { s0.x, s1.x, s0.y, s1.y };   // PV A-frag, kpos tile 0..15
    uint4v w1v = { s2.x, s3.x, s2.y, s3.y };   // kpos tile 16..31
    short8 pa0 = __builtin_bit_cast(short8, w0v);
    short8 pa1 = __builtin_bit_cast(short8, w1v);

    acc = MFMA32(pa0, v0, acc);
    acc = MFMA32(pa1, v1, acc);
}

__global__ __launch_bounds__(256) void flash_kernel(
    const short* __restrict__ Q, const short* __restrict__ K, const short* __restrict__ Vt,
    short* __restrict__ Af)
{
    __shared__ float llds[4][2][32];

    // consecutive idx = consecutive bh (round-robin XCD); the 4 q-blocks of
    // one bh are 256 apart -> same XCD (256 % 8 == 0) -> K/V L2 locality
    int idx = blockIdx.x;
    int bh = idx & 255;
    int qb = idx >> 8;          // 0..3
    int b = bh >> 3, h = bh & 7;

    int tid = threadIdx.x;
    int lane = tid & 63, w = tid >> 6;
    int l31 = lane & 31;
    int hi = lane >> 5;

    int qrA = qb * 256 + w * 32;
    int qrB = qrA + 128;

    // Q B-fragments (col = q = l31, k-dim = head-dim e), loop-invariant
    const short* QpA = Q + ((size_t)bh * SS + qrA + l31) * DHP + hi * 8;
    const short* QpB = Q + ((size_t)bh * SS + qrB + l31) * DHP + hi * 8;
    short8 qA0 = *(const short8*)QpA;          // e = hi*8 + j
    short8 qA1 = *(const short8*)(QpA + 16);   // e = 16 + hi*8 + j
    short8 qB0 = *(const short8*)QpB;
    short8 qB1 = *(const short8*)(QpB + 16);

    const short* Kp = K + ((size_t)bh * SS + l31) * DHP + hi * 8;
    const short* Vp = Vt + ((size_t)bh * DHP + l31) * SS + hi * 8;

    f32x16 accA, accB, Z16;
    #pragma unroll
    for (int r = 0; r < 16; r++) { accA[r] = 0.f; accB[r] = 0.f; Z16[r] = 0.f; }

    for (int kt = 0; kt < 32; kt++) {
        short8 k0 = *(const short8*)(Kp);        // A: row = kpos, kdim e 0..15
        short8 k1 = *(const short8*)(Kp + 16);   //                kdim e 16..31
        short8 v0 = *(const short8*)(Vp);        // B: col = e, k = kpos 0..15
        short8 v1 = *(const short8*)(Vp + 16);   //             k = kpos 16..31
        Kp += 32 * DHP;
        Vp += 32;

        // S[kpos][q]: col = q = l31, row = kpos = (r&3) + 8*(r>>2) + 4*hi
        // D != C on MFMA: seed with loop-invariant zero tuple (no mov burst)
        f32x16 SA = MFMA32(k0, qA0, Z16);
        SA = MFMA32(k1, qA1, SA);   // includes mask bias via channel e=31
        f32x16 SB = MFMA32(k0, qB0, Z16);
        SB = MFMA32(k1, qB1, SB);

        fproc(SA, accA, v0, v1);
        fproc(SB, accB, v0, v1);
    }

    // denominator came through V's ones-column: acc col 24 (lanes l31==24)
    if (l31 == 24) {
        #pragma unroll
        for (int r = 0; r < 16; r++) {
            int row = (r & 3) + 8 * (r >> 2) + 4 * hi;
            llds[w][0][row] = __builtin_amdgcn_rcpf(accA[r]);
            llds[w][1][row] = __builtin_amdgcn_rcpf(accB[r]);
        }
    }
    __builtin_amdgcn_wave_barrier();   // same-wave LDS ordering fence

    // store O into fragment-order Af[(grow>>4)*24 + kk*4+g][c=row&15][8]
    // col d = h*24 + l31; row = (r&3) + 8*(r>>2) + 4*hi; grow = b*SS + qr + row
    if (l31 < 24) {
        int d = h * 24 + l31;
        int grpA = (b * SS + qrA) >> 4;
        int grpB = (b * SS + qrB) >> 4;
        size_t fcol = (size_t)((d >> 5) * 4 + ((d >> 3) & 3)) * 128 + (d & 7);
        short* opA = Af + (size_t)grpA * 3072 + fcol;   // 3072 = 24*128
        short* opB = Af + (size_t)grpB * 3072 + fcol;
        #pragma unroll
        for (int r = 0; r < 16; r++) {
            int row = (r & 3) + 8 * (r >> 2) + 4 * hi;
            size_t off = (size_t)(r >> 3) * 3072 + (size_t)(row & 15) * 8;
            opA[off] = nb(accA[r] * llds[w][0][row]);
            opB[off] = nb(accB[r] * llds[w][1][row]);
        }
    }
}

// ---------------- final: out = attn(bf16) @ Wo + bo (Wo split hi+lo) ----------------
// blockIdx.y selects half of the 12 output n-tiles
__global__ __launch_bounds__(256) void final_kernel(
    const short* __restrict__ Af,
    const short* __restrict__ WoFh, const short* __restrict__ WoFl,
    const float* __restrict__ bo, float* __restrict__ out)
{
    int tid = threadIdx.x;
    int lane = tid & 63, w = tid >> 6;
    int c = lane & 15, g = lane >> 4;
    int r0 = blockIdx.x * 64 + w * 16;
    int n0 = blockIdx.y * 6;

    short8 a[6];
    #pragma unroll
    for (int kk = 0; kk < 6; kk++)
        a[kk] = *(const short8*)(Af + ((size_t)(r0 >> 4) * 24 + kk*4 + g) * 128 + c * 8);

    f32x4 acc[6];
    #pragma unroll
    for (int n = 0; n < 6; n++) acc[n] = (f32x4){0.f,0.f,0.f,0.f};

    #pragma unroll
    for (int kk = 0; kk < 6; kk++) {
        #pragma unroll
        for (int n = 0; n < 6; n++) {
            const short* bh_p = WoFh + (size_t)((n0+n)*6 + kk) * 512 + lane * 8;
            const short* bl_p = WoFl + (size_t)((n0+n)*6 + kk) * 512 + lane * 8;
            short8 bh = *(const short8*)bh_p;
            short8 bl = *(const short8*)bl_p;
            acc[n] = MFMA16(a[kk], bh, acc[n]);
            acc[n] = MFMA16(a[kk], bl, acc[n]);
        }
    }

    #pragma unroll
    for (int n = 0; n < 6; n++) {
        int col = (n0+n)*16 + c;
        float bv = bo[col];
        #pragma unroll
        for (int r = 0; r < 4; r++) {
            out[(size_t)(r0 + g*4 + r) * DD + col] = acc[n][r] + bv;
        }
    }
}

extern "C" void kernel_launch(void* const* d_in, const int* in_sizes, int n_in,
                              void* d_out, int out_size, void* d_ws, size_t ws_size,
                              hipStream_t stream)
{
    const float* x    = (const float*)d_in[0];
    const void*  mask = d_in[1];
    const float* Wq   = (const float*)d_in[2];
    const float* bq   = (const float*)d_in[3];
    const float* Wk   = (const float*)d_in[4];
    const float* bk   = (const float*)d_in[5];
    const float* Wv   = (const float*)d_in[6];
    const float* bv   = (const float*)d_in[7];
    const float* Wo   = (const float*)d_in[8];
    const float* bo   = (const float*)d_in[9];
    float* out = (float*)d_out;

    char* ws = (char*)d_ws;
    size_t off = 0;
    float* maskf = (float*)(ws + off); off += (size_t)BB*SS*4;          // 128 KB
    short* Q     = (short*)(ws + off); off += (size_t)BB*HH*SS*DHP*2;   // 16 MB
    short* K     = (short*)(ws + off); off += (size_t)BB*HH*SS*DHP*2;   // 16 MB
    short* Vt    = (short*)(ws + off); off += (size_t)BB*HH*SS*DHP*2;   // 16 MB
    short* Af    = (short*)(ws + off); off += (size_t)BB*SS*DD*2;       // 12 MB
    short* WqF   = (short*)(ws + off); off += (size_t)HH*DHP*DD*2;
    short* WkF   = (short*)(ws + off); off += (size_t)HH*DHP*DD*2;
    short* WvF   = (short*)(ws + off); off += (size_t)HH*DHP*DD*2;
    short* WoFh  = (short*)(ws + off); off += (size_t)DD*DD*2;
    short* WoFl  = (short*)(ws + off); off += (size_t)DD*DD*2;

    prep_kernel<<<dim3(848), dim3(256), 0, stream>>>(
        mask, Wq, Wk, Wv, Wo, maskf, WqF, WkF, WvF, WoFh, WoFl);
    proj_kernel<<<dim3(512), dim3(256), 0, stream>>>(
        x, bq, bk, bv, WqF, WkF, WvF, maskf, Q, K, Vt);
    flash_kernel<<<dim3(1024), dim3(256), 0, stream>>>(
        Q, K, Vt, Af);
    final_kernel<<<dim3(512, 2), dim3(256), 0, stream>>>(
        Af, WoFh, WoFl, bo, out);
}

// Round 8
// 118.376 us; speedup vs baseline: 1.6335x; 1.0355x over previous
//
#include <hip/hip_runtime.h>

typedef __attribute__((ext_vector_type(8))) short short8;
typedef __attribute__((ext_vector_type(4))) short short4v;
typedef __attribute__((ext_vector_type(4))) float f32x4;
typedef __attribute__((ext_vector_type(16))) float f32x16;
typedef __attribute__((ext_vector_type(2))) unsigned uint2v;
typedef __attribute__((ext_vector_type(4))) unsigned uint4v;

#define MFMA16(a,b,c) __builtin_amdgcn_mfma_f32_16x16x32_bf16((a),(b),(c),0,0,0)
#define MFMA32(a,b,c) __builtin_amdgcn_mfma_f32_32x32x16_bf16((a),(b),(c),0,0,0)

#define BB 32
#define SS 1024
#define DD 192
#define HH 8
#define DHP 32   // padded head dim (24 -> 32); col 31 = mask-bias, col 24 of V = ones

// Q pre-scale: log2(e) / sqrt(24)  -> exp2(S) == softmax numerator
#define SCALE_Q 0.294468266742895f

// native RNE conversions (compiler emits v_cvt_*_bf16, fuses pairs to cvt_pk)
__device__ __forceinline__ short nb(float f) {
    __bf16 h = (__bf16)f;
    return __builtin_bit_cast(short, h);
}
__device__ __forceinline__ float bf2f(short s) {
    union { unsigned u; float f; } v; v.u = ((unsigned)(unsigned short)s) << 16;
    return v.f;
}
__device__ __forceinline__ unsigned pk2(float a, float b) {
    unsigned short lo = __builtin_bit_cast(unsigned short, (__bf16)a);
    unsigned short hi = __builtin_bit_cast(unsigned short, (__bf16)b);
    return (unsigned)lo | ((unsigned)hi << 16);
}

// ---------------- prep: mask normalize + fragment-order weight layouts ----------------
__global__ __launch_bounds__(256) void prep_kernel(
    const void* __restrict__ mask_raw,
    const float* __restrict__ Wq, const float* __restrict__ Wk, const float* __restrict__ Wv,
    const float* __restrict__ Wo,
    float* __restrict__ maskf,
    short* __restrict__ WqF, short* __restrict__ WkF, short* __restrict__ WvF,
    short* __restrict__ WoFh, short* __restrict__ WoFl)
{
    int idx = blockIdx.x * 256 + threadIdx.x;
    const int NMASK = BB * SS;               // 32768
    const int NWX   = 3 * HH * DHP * DD;     // 147456
    const int NWO   = DD * DD;               // 36864
    if (idx < NMASK) {
        // dtype sniff: bool may arrive as int32 (0/1), float32 (0.0/1.0) or uint8
        const unsigned* mw = (const unsigned*)mask_raw;
        bool all01 = true, allf = true;
        #pragma unroll
        for (int i = 0; i < 16; i++) {
            unsigned w = mw[i];
            all01 = all01 && (w <= 1u);
            allf  = allf  && (w == 0u || w == 0x3F800000u);
        }
        float m;
        if (all01)      m = (mw[idx] != 0u) ? 1.f : 0.f;
        else if (allf)  m = (((const float*)mask_raw)[idx] != 0.f) ? 1.f : 0.f;
        else            m = (((const unsigned char*)mask_raw)[idx] != 0) ? 1.f : 0.f;
        maskf[idx] = m;
    } else if (idx < NMASK + NWX) {
        int j = idx - NMASK;
        int mat = j / (HH * DHP * DD);
        int jj  = j % (HH * DHP * DD);
        int h   = jj / (DHP * DD);
        int rem = jj % (DHP * DD);
        int e   = rem / DD;       // actual output col 0..31
        int d   = rem % DD;       // input dim
        const float* W = (mat == 0) ? Wq : (mat == 1) ? Wk : Wv;
        short* WF      = (mat == 0) ? WqF : (mat == 1) ? WkF : WvF;
        float val = (e < 24) ? W[(h * DD + d) * 24 + e] : 0.f;   // pad e>=24 with 0
        int nt = e & 1, cc = e >> 1;
        int kk = d >> 5, g = (d >> 3) & 3, ee = d & 7;
        WF[(size_t)((((h*2+nt)*6 + kk)*64) + g*16 + cc)*8 + ee] = nb(val);
    } else if (idx < NMASK + NWX + NWO) {
        int j = idx - NMASK - NWX;
        int n = j / DD, k = j % DD;    // n = out col, k = in dim
        float f = Wo[k * DD + n];
        short hi = nb(f);
        int nn = n >> 4, cc = n & 15;
        int kk = k >> 5, g = (k >> 3) & 3, ee = k & 7;
        size_t addr = (size_t)(((nn*6 + kk)*64) + g*16 + cc)*8 + ee;
        WoFh[addr] = hi;
        WoFl[addr] = nb(f - bf2f(hi));   // split-bf16 low part
    }
}

// ---------------- scan: per-batch mask compaction map ----------------
// inv[b][s]: unmasked rows -> 0..cnt-1 (stable order); masked rows -> cnt..1023
__global__ __launch_bounds__(1024) void scan_kernel(
    const float* __restrict__ maskf, int* __restrict__ inv, int* __restrict__ cnt)
{
    int b = blockIdx.x, t = threadIdx.x;
    int lane = t & 63, wv = t >> 6;
    bool m = maskf[b * SS + t] != 0.f;
    unsigned long long bal = __ballot(m);
    int preU  = __popcll(bal & ((1ull << lane) - 1ull));
    int waveU = __popcll(bal);
    __shared__ int wsu[16];
    if (lane == 0) wsu[wv] = waveU;
    __syncthreads();
    int waveOffU = 0, totalU = 0;
    #pragma unroll
    for (int i = 0; i < 16; i++) {
        int v = wsu[i];
        if (i < wv) waveOffU += v;
        totalU += v;
    }
    int posU = waveOffU + preU;
    int posM = totalU + (wv * 64 - waveOffU) + (lane - preU);
    inv[b * SS + t] = m ? posU : posM;
    if (t == 0) cnt[b] = totalU;
}

// ---------------- proj: Q/K/V = x @ W + b via MFMA (coalesced weight frags) ----------------
// Q natural order; K and Vc stored at compacted row inv[b][s].
// Q[:,31] = 1.0; K[:,31] = mask ? 0 : -1e30; Vc[:,24] = 1.0 (denominator column)
__global__ __launch_bounds__(256) void proj_kernel(
    const float* __restrict__ x,
    const float* __restrict__ bq, const float* __restrict__ bk, const float* __restrict__ bv,
    const short* __restrict__ WqF, const short* __restrict__ WkF, const short* __restrict__ WvF,
    const float* __restrict__ maskf, const int* __restrict__ inv,
    short* __restrict__ Q, short* __restrict__ K, short* __restrict__ Vc)
{
    int tid = threadIdx.x;
    int lane = tid & 63, w = tid >> 6;
    int c = lane & 15, g = lane >> 4;
    int r0 = blockIdx.x * 64 + w * 16;
    int arow = r0 + c;

    // output row block for this thread: rows s0..s0+3 (same batch: 64 | 1024)
    int b_ = r0 >> 10;
    int s0 = (r0 & 1023) + g * 4;

    short8 a[6];
    #pragma unroll
    for (int kk = 0; kk < 6; kk++) {
        const float* px = x + (size_t)arow * DD + kk * 32 + g * 8;
        float4 f0 = *(const float4*)px;
        float4 f1 = *(const float4*)(px + 4);
        short8 t;
        t[0]=nb(f0.x); t[1]=nb(f0.y); t[2]=nb(f0.z); t[3]=nb(f0.w);
        t[4]=nb(f1.x); t[5]=nb(f1.y); t[6]=nb(f1.z); t[7]=nb(f1.w);
        a[kk] = t;
    }

    float mrow[4];
    int dst[4];
    #pragma unroll
    for (int r = 0; r < 4; r++) {
        mrow[r] = maskf[b_ * SS + s0 + r];
        dst[r]  = inv[b_ * SS + s0 + r];
    }

    for (int h = 0; h < HH; h++) {
        int bh = b_ * HH + h;
        #pragma unroll
        for (int mat = 0; mat < 3; mat++) {
            const short* WF   = (mat==0)?WqF:(mat==1)?WkF:WvF;
            const float* bias = (mat==0)?bq:(mat==1)?bk:bv;

            f32x4 acc0 = {0.f,0.f,0.f,0.f};   // actual col 2c
            f32x4 acc1 = {0.f,0.f,0.f,0.f};   // actual col 2c+1
            const short* Wp0 = WF + (size_t)((h*2+0)*6) * 512 + lane * 8;
            const short* Wp1 = WF + (size_t)((h*2+1)*6) * 512 + lane * 8;
            #pragma unroll
            for (int kk = 0; kk < 6; kk++) {
                short8 b0 = *(const short8*)(Wp0 + kk * 512);
                short8 b1 = *(const short8*)(Wp1 + kk * 512);
                acc0 = MFMA16(a[kk], b0, acc0);
                acc1 = MFMA16(a[kk], b1, acc1);
            }
            float bv0 = 0.f, bv1 = 0.f;
            if (2*c < 24) {
                float2 bb = *(const float2*)(bias + h * 24 + 2 * c);
                bv0 = bb.x; bv1 = bb.y;
            }

            if (mat == 0) {
                #pragma unroll
                for (int r = 0; r < 4; r++) {
                    float v0 = (acc0[r] + bv0) * SCALE_Q;
                    float v1 = (c == 15) ? 1.0f : (acc1[r] + bv1) * SCALE_Q;
                    *(unsigned*)(Q + ((size_t)bh * SS + s0 + r) * DHP + 2*c) = pk2(v0, v1);
                }
            } else if (mat == 1) {
                #pragma unroll
                for (int r = 0; r < 4; r++) {
                    float v0 = acc0[r] + bv0;
                    float v1 = (c == 15) ? ((mrow[r] != 0.f) ? 0.f : -1e30f)
                                         : (acc1[r] + bv1);
                    *(unsigned*)(K + ((size_t)bh * SS + dst[r]) * DHP + 2*c) = pk2(v0, v1);
                }
            } else {
                #pragma unroll
                for (int r = 0; r < 4; r++) {
                    float v0 = (c == 12) ? 1.0f : (acc0[r] + bv0);  // col 24 = ones
                    float v1 = acc1[r] + bv1;
                    *(unsigned*)(Vc + ((size_t)bh * SS + dst[r]) * DHP + 2*c) = pk2(v0, v1);
                }
            }
        }
    }
}

// ---------------- vtrans: Vc[s_c][e] -> Vt[e][s_c] (LDS tile transpose) ----------------
__global__ __launch_bounds__(256) void vtrans_kernel(
    const short* __restrict__ Vc, short* __restrict__ Vt)
{
    __shared__ short tile[256][33];
    int bh = blockIdx.x, c4 = blockIdx.y;
    int t = threadIdx.x;
    const short* src = Vc + ((size_t)bh * SS + c4 * 256 + t) * DHP;
    short8 a0 = *(const short8*)(src);
    short8 a1 = *(const short8*)(src + 8);
    short8 a2 = *(const short8*)(src + 16);
    short8 a3 = *(const short8*)(src + 24);
    #pragma unroll
    for (int i = 0; i < 8; i++) {
        tile[t][i]      = a0[i];
        tile[t][8 + i]  = a1[i];
        tile[t][16 + i] = a2[i];
        tile[t][24 + i] = a3[i];
    }
    __syncthreads();
    int e = t & 31, jg = t >> 5;
    if (e < 25) {   // Vt rows 25..31 never read by flash (acc cols unused)
        short* dstp = Vt + ((size_t)bh * DHP + e) * SS + c4 * 256 + jg * 32;
        short8 o[4];
        #pragma unroll
        for (int i = 0; i < 32; i++) o[i >> 3][i & 7] = tile[jg * 32 + i][e];
        #pragma unroll
        for (int i = 0; i < 4; i++) *(short8*)(dstp + i * 8) = o[i];
    }
}

// ---------------- flash attention (swapped QK^T, in-register softmax) ----------------
__device__ __forceinline__ void fproc(const f32x16& S, f32x16& acc,
                                      short8 v0, short8 v1)
{
    float p[16];
    #pragma unroll
    for (int r = 0; r < 16; r++) p[r] = __builtin_amdgcn_exp2f(S[r]);

    unsigned c01 = pk2(p[0],  p[1]);
    unsigned c23 = pk2(p[2],  p[3]);
    unsigned c45 = pk2(p[4],  p[5]);
    unsigned c67 = pk2(p[6],  p[7]);
    unsigned c89 = pk2(p[8],  p[9]);
    unsigned cab = pk2(p[10], p[11]);
    unsigned ccd = pk2(p[12], p[13]);
    unsigned cef = pk2(p[14], p[15]);

    // permlane32_swap(a,b): x[l] = l<32 ? a[l] : b[l-32]
    //                       y[l] = l<32 ? a[l+32] : b[l]
    uint2v s0 = __builtin_amdgcn_permlane32_swap(c01, c45, false, false);
    uint2v s1 = __builtin_amdgcn_permlane32_swap(c23, c67, false, false);
    uint2v s2 = __builtin_amdgcn_permlane32_swap(c89, ccd, false, false);
    uint2v s3 = __builtin_amdgcn_permlane32_swap(cab, cef, false, false);

    uint4v w0v = { s0.x, s1.x, s0.y, s1.y };   // PV A-frag, kpos tile 0..15
    uint4v w1v = { s2.x, s3.x, s2.y, s3.y };   // kpos tile 16..31
    short8 pa0 = __builtin_bit_cast(short8, w0v);
    short8 pa1 = __builtin_bit_cast(short8, w1v);

    acc = MFMA32(pa0, v0, acc);
    acc = MFMA32(pa1, v1, acc);
}

__global__ __launch_bounds__(256) void flash_kernel(
    const short* __restrict__ Q, const short* __restrict__ K, const short* __restrict__ Vt,
    const int* __restrict__ cnt, short* __restrict__ Af)
{
    __shared__ float llds[4][2][32];

    int idx = blockIdx.x;
    int bh = idx & 255;
    int qb = idx >> 8;          // 0..3
    int b = bh >> 3, h = bh & 7;

    int tid = threadIdx.x;
    int lane = tid & 63, w = tid >> 6;
    int l31 = lane & 31;
    int hi = lane >> 5;

    int nt = (cnt[b] + 31) >> 5;   // only tiles containing unmasked positions

    int qrA = qb * 256 + w * 32;
    int qrB = qrA + 128;

    const short* QpA = Q + ((size_t)bh * SS + qrA + l31) * DHP + hi * 8;
    const short* QpB = Q + ((size_t)bh * SS + qrB + l31) * DHP + hi * 8;
    short8 qA0 = *(const short8*)QpA;
    short8 qA1 = *(const short8*)(QpA + 16);
    short8 qB0 = *(const short8*)QpB;
    short8 qB1 = *(const short8*)(QpB + 16);

    const short* Kp = K + ((size_t)bh * SS + l31) * DHP + hi * 8;
    const short* Vp = Vt + ((size_t)bh * DHP + l31) * SS + hi * 8;

    f32x16 accA, accB, Z16;
    #pragma unroll
    for (int r = 0; r < 16; r++) { accA[r] = 0.f; accB[r] = 0.f; Z16[r] = 0.f; }

    for (int kt = 0; kt < nt; kt++) {
        short8 k0 = *(const short8*)(Kp);
        short8 k1 = *(const short8*)(Kp + 16);
        short8 v0 = *(const short8*)(Vp);
        short8 v1 = *(const short8*)(Vp + 16);
        Kp += 32 * DHP;
        Vp += 32;

        f32x16 SA = MFMA32(k0, qA0, Z16);
        SA = MFMA32(k1, qA1, SA);   // includes mask bias via channel e=31
        f32x16 SB = MFMA32(k0, qB0, Z16);
        SB = MFMA32(k1, qB1, SB);

        fproc(SA, accA, v0, v1);
        fproc(SB, accB, v0, v1);
    }

    // denominator via V's ones-column: acc col 24 (lanes l31==24)
    if (l31 == 24) {
        #pragma unroll
        for (int r = 0; r < 16; r++) {
            int row = (r & 3) + 8 * (r >> 2) + 4 * hi;
            llds[w][0][row] = __builtin_amdgcn_rcpf(accA[r]);
            llds[w][1][row] = __builtin_amdgcn_rcpf(accB[r]);
        }
    }
    __builtin_amdgcn_wave_barrier();   // same-wave LDS ordering fence

    // store O into fragment-order Af[(grow>>4)*24 + kk*4+g][c=row&15][8]
    if (l31 < 24) {
        int d = h * 24 + l31;
        int grpA = (b * SS + qrA) >> 4;
        int grpB = (b * SS + qrB) >> 4;
        size_t fcol = (size_t)((d >> 5) * 4 + ((d >> 3) & 3)) * 128 + (d & 7);
        short* opA = Af + (size_t)grpA * 3072 + fcol;   // 3072 = 24*128
        short* opB = Af + (size_t)grpB * 3072 + fcol;
        #pragma unroll
        for (int r = 0; r < 16; r++) {
            int row = (r & 3) + 8 * (r >> 2) + 4 * hi;
            size_t off = (size_t)(r >> 3) * 3072 + (size_t)(row & 15) * 8;
            opA[off] = nb(accA[r] * llds[w][0][row]);
            opB[off] = nb(accB[r] * llds[w][1][row]);
        }
    }
}

// ---------------- final: out = attn(bf16) @ Wo + bo (Wo split hi+lo) ----------------
__global__ __launch_bounds__(256) void final_kernel(
    const short* __restrict__ Af,
    const short* __restrict__ WoFh, const short* __restrict__ WoFl,
    const float* __restrict__ bo, float* __restrict__ out)
{
    int tid = threadIdx.x;
    int lane = tid & 63, w = tid >> 6;
    int c = lane & 15, g = lane >> 4;
    int r0 = blockIdx.x * 64 + w * 16;
    int n0 = blockIdx.y * 6;

    short8 a[6];
    #pragma unroll
    for (int kk = 0; kk < 6; kk++)
        a[kk] = *(const short8*)(Af + ((size_t)(r0 >> 4) * 24 + kk*4 + g) * 128 + c * 8);

    f32x4 acc[6];
    #pragma unroll
    for (int n = 0; n < 6; n++) acc[n] = (f32x4){0.f,0.f,0.f,0.f};

    #pragma unroll
    for (int kk = 0; kk < 6; kk++) {
        #pragma unroll
        for (int n = 0; n < 6; n++) {
            const short* bh_p = WoFh + (size_t)((n0+n)*6 + kk) * 512 + lane * 8;
            const short* bl_p = WoFl + (size_t)((n0+n)*6 + kk) * 512 + lane * 8;
            short8 bh = *(const short8*)bh_p;
            short8 bl = *(const short8*)bl_p;
            acc[n] = MFMA16(a[kk], bh, acc[n]);
            acc[n] = MFMA16(a[kk], bl, acc[n]);
        }
    }

    #pragma unroll
    for (int n = 0; n < 6; n++) {
        int col = (n0+n)*16 + c;
        float bv = bo[col];
        #pragma unroll
        for (int r = 0; r < 4; r++) {
            out[(size_t)(r0 + g*4 + r) * DD + col] = acc[n][r] + bv;
        }
    }
}

extern "C" void kernel_launch(void* const* d_in, const int* in_sizes, int n_in,
                              void* d_out, int out_size, void* d_ws, size_t ws_size,
                              hipStream_t stream)
{
    const float* x    = (const float*)d_in[0];
    const void*  mask = d_in[1];
    const float* Wq   = (const float*)d_in[2];
    const float* bq   = (const float*)d_in[3];
    const float* Wk   = (const float*)d_in[4];
    const float* bk   = (const float*)d_in[5];
    const float* Wv   = (const float*)d_in[6];
    const float* bv   = (const float*)d_in[7];
    const float* Wo   = (const float*)d_in[8];
    const float* bo   = (const float*)d_in[9];
    float* out = (float*)d_out;

    char* ws = (char*)d_ws;
    size_t off = 0;
    float* maskf = (float*)(ws + off); off += (size_t)BB*SS*4;          // 128 KB
    short* Q     = (short*)(ws + off); off += (size_t)BB*HH*SS*DHP*2;   // 16 MB
    short* K     = (short*)(ws + off); off += (size_t)BB*HH*SS*DHP*2;   // 16 MB
    short* Vt    = (short*)(ws + off); off += (size_t)BB*HH*SS*DHP*2;   // 16 MB
    short* Af    = (short*)(ws + off); off += (size_t)BB*SS*DD*2;       // 12 MB
    short* WqF   = (short*)(ws + off); off += (size_t)HH*DHP*DD*2;
    short* WkF   = (short*)(ws + off); off += (size_t)HH*DHP*DD*2;
    short* WvF   = (short*)(ws + off); off += (size_t)HH*DHP*DD*2;
    short* WoFh  = (short*)(ws + off); off += (size_t)DD*DD*2;
    short* WoFl  = (short*)(ws + off); off += (size_t)DD*DD*2;
    short* Vc    = (short*)(ws + off); off += (size_t)BB*HH*SS*DHP*2;   // 16 MB
    int*   inv   = (int*)  (ws + off); off += (size_t)BB*SS*4;          // 128 KB
    int*   cnt   = (int*)  (ws + off); off += 256;

    prep_kernel<<<dim3(848), dim3(256), 0, stream>>>(
        mask, Wq, Wk, Wv, Wo, maskf, WqF, WkF, WvF, WoFh, WoFl);
    scan_kernel<<<dim3(BB), dim3(1024), 0, stream>>>(maskf, inv, cnt);
    proj_kernel<<<dim3(512), dim3(256), 0, stream>>>(
        x, bq, bk, bv, WqF, WkF, WvF, maskf, inv, Q, K, Vc);
    vtrans_kernel<<<dim3(256, 4), dim3(256), 0, stream>>>(Vc, Vt);
    flash_kernel<<<dim3(1024), dim3(256), 0, stream>>>(
        Q, K, Vt, cnt, Af);
    final_kernel<<<dim3(512, 2), dim3(256), 0, stream>>>(
        Af, WoFh, WoFl, bo, out);
}

// Round 9
// 109.229 us; speedup vs baseline: 1.7703x; 1.0837x over previous
//
#include <hip/hip_runtime.h>

typedef __attribute__((ext_vector_type(8))) short short8;
typedef __attribute__((ext_vector_type(4))) short short4v;
typedef __attribute__((ext_vector_type(4))) float f32x4;
typedef __attribute__((ext_vector_type(16))) float f32x16;
typedef __attribute__((ext_vector_type(2))) unsigned uint2v;
typedef __attribute__((ext_vector_type(4))) unsigned uint4v;

#define MFMA16(a,b,c) __builtin_amdgcn_mfma_f32_16x16x32_bf16((a),(b),(c),0,0,0)
#define MFMA32(a,b,c) __builtin_amdgcn_mfma_f32_32x32x16_bf16((a),(b),(c),0,0,0)

#define BB 32
#define SS 1024
#define DD 192
#define HH 8
#define DHP 32   // padded head dim (24 -> 32); col 31 = mask-bias, col 24 of V = ones

// Q pre-scale: log2(e) / sqrt(24)  -> exp2(S) == softmax numerator
#define SCALE_Q 0.294468266742895f

// native RNE conversions (compiler emits v_cvt_*_bf16, fuses pairs to cvt_pk)
__device__ __forceinline__ short nb(float f) {
    __bf16 h = (__bf16)f;
    return __builtin_bit_cast(short, h);
}
__device__ __forceinline__ float bf2f(short s) {
    union { unsigned u; float f; } v; v.u = ((unsigned)(unsigned short)s) << 16;
    return v.f;
}
__device__ __forceinline__ unsigned pk2(float a, float b) {
    unsigned short lo = __builtin_bit_cast(unsigned short, (__bf16)a);
    unsigned short hi = __builtin_bit_cast(unsigned short, (__bf16)b);
    return (unsigned)lo | ((unsigned)hi << 16);
}

// ---------------- prep: mask normalize + fragment-order weight layouts ----------------
__global__ __launch_bounds__(256) void prep_kernel(
    const void* __restrict__ mask_raw,
    const float* __restrict__ Wq, const float* __restrict__ Wk, const float* __restrict__ Wv,
    const float* __restrict__ Wo,
    float* __restrict__ maskf,
    short* __restrict__ WqF, short* __restrict__ WkF, short* __restrict__ WvF,
    short* __restrict__ WoFh, short* __restrict__ WoFl)
{
    int idx = blockIdx.x * 256 + threadIdx.x;
    const int NMASK = BB * SS;               // 32768
    const int NWX   = 3 * HH * DHP * DD;     // 147456
    const int NWO   = DD * DD;               // 36864
    if (idx < NMASK) {
        // dtype sniff: bool may arrive as int32 (0/1), float32 (0.0/1.0) or uint8
        const unsigned* mw = (const unsigned*)mask_raw;
        bool all01 = true, allf = true;
        #pragma unroll
        for (int i = 0; i < 16; i++) {
            unsigned w = mw[i];
            all01 = all01 && (w <= 1u);
            allf  = allf  && (w == 0u || w == 0x3F800000u);
        }
        float m;
        if (all01)      m = (mw[idx] != 0u) ? 1.f : 0.f;
        else if (allf)  m = (((const float*)mask_raw)[idx] != 0.f) ? 1.f : 0.f;
        else            m = (((const unsigned char*)mask_raw)[idx] != 0) ? 1.f : 0.f;
        maskf[idx] = m;
    } else if (idx < NMASK + NWX) {
        int j = idx - NMASK;
        int mat = j / (HH * DHP * DD);
        int jj  = j % (HH * DHP * DD);
        int h   = jj / (DHP * DD);
        int rem = jj % (DHP * DD);
        int e   = rem / DD;       // actual output col 0..31
        int d   = rem % DD;       // input dim
        const float* W = (mat == 0) ? Wq : (mat == 1) ? Wk : Wv;
        short* WF      = (mat == 0) ? WqF : (mat == 1) ? WkF : WvF;
        float val = (e < 24) ? W[(h * DD + d) * 24 + e] : 0.f;   // pad e>=24 with 0
        int nt = e & 1, cc = e >> 1;
        int kk = d >> 5, g = (d >> 3) & 3, ee = d & 7;
        WF[(size_t)((((h*2+nt)*6 + kk)*64) + g*16 + cc)*8 + ee] = nb(val);
    } else if (idx < NMASK + NWX + NWO) {
        int j = idx - NMASK - NWX;
        int n = j / DD, k = j % DD;    // n = out col, k = in dim
        float f = Wo[k * DD + n];
        short hi = nb(f);
        int nn = n >> 4, cc = n & 15;
        int kk = k >> 5, g = (k >> 3) & 3, ee = k & 7;
        size_t addr = (size_t)(((nn*6 + kk)*64) + g*16 + cc)*8 + ee;
        WoFh[addr] = hi;
        WoFl[addr] = nb(f - bf2f(hi));   // split-bf16 low part
    }
}

// ---------------- scan: per-batch mask compaction map ----------------
// inv[b][s]: unmasked rows -> 0..cnt-1 (stable order); masked rows -> cnt..1023
__global__ __launch_bounds__(1024) void scan_kernel(
    const float* __restrict__ maskf, int* __restrict__ inv, int* __restrict__ cnt)
{
    int b = blockIdx.x, t = threadIdx.x;
    int lane = t & 63, wv = t >> 6;
    bool m = maskf[b * SS + t] != 0.f;
    unsigned long long bal = __ballot(m);
    int preU  = __popcll(bal & ((1ull << lane) - 1ull));
    int waveU = __popcll(bal);
    __shared__ int wsu[16];
    if (lane == 0) wsu[wv] = waveU;
    __syncthreads();
    int waveOffU = 0, totalU = 0;
    #pragma unroll
    for (int i = 0; i < 16; i++) {
        int v = wsu[i];
        if (i < wv) waveOffU += v;
        totalU += v;
    }
    int posU = waveOffU + preU;
    int posM = totalU + (wv * 64 - waveOffU) + (lane - preU);
    inv[b * SS + t] = m ? posU : posM;
    if (t == 0) cnt[b] = totalU;
}

// ---------------- proj: Q/K/V = x @ W + b via MFMA (coalesced weight frags) ----------------
// blockIdx.y = head-pair (heads 2y, 2y+1) — 2048 blocks = 8/CU for latency hiding.
// Q natural order; K and Vc stored at compacted row inv[b][s].
// Q[:,31] = 1.0; K[:,31] = mask ? 0 : -1e30; Vc[:,24] = 1.0 (denominator column)
__global__ __launch_bounds__(256) void proj_kernel(
    const float* __restrict__ x,
    const float* __restrict__ bq, const float* __restrict__ bk, const float* __restrict__ bv,
    const short* __restrict__ WqF, const short* __restrict__ WkF, const short* __restrict__ WvF,
    const float* __restrict__ maskf, const int* __restrict__ inv,
    short* __restrict__ Q, short* __restrict__ K, short* __restrict__ Vc)
{
    int tid = threadIdx.x;
    int lane = tid & 63, w = tid >> 6;
    int c = lane & 15, g = lane >> 4;
    int r0 = blockIdx.x * 64 + w * 16;
    int arow = r0 + c;
    int h0 = blockIdx.y * 2;

    // output row block for this thread: rows s0..s0+3 (same batch: 64 | 1024)
    int b_ = r0 >> 10;
    int s0 = (r0 & 1023) + g * 4;

    short8 a[6];
    #pragma unroll
    for (int kk = 0; kk < 6; kk++) {
        const float* px = x + (size_t)arow * DD + kk * 32 + g * 8;
        float4 f0 = *(const float4*)px;
        float4 f1 = *(const float4*)(px + 4);
        short8 t;
        t[0]=nb(f0.x); t[1]=nb(f0.y); t[2]=nb(f0.z); t[3]=nb(f0.w);
        t[4]=nb(f1.x); t[5]=nb(f1.y); t[6]=nb(f1.z); t[7]=nb(f1.w);
        a[kk] = t;
    }

    float mrow[4];
    int dst[4];
    #pragma unroll
    for (int r = 0; r < 4; r++) {
        mrow[r] = maskf[b_ * SS + s0 + r];
        dst[r]  = inv[b_ * SS + s0 + r];
    }

    #pragma unroll
    for (int hh = 0; hh < 2; hh++) {
        int h = h0 + hh;
        int bh = b_ * HH + h;
        #pragma unroll
        for (int mat = 0; mat < 3; mat++) {
            const short* WF   = (mat==0)?WqF:(mat==1)?WkF:WvF;
            const float* bias = (mat==0)?bq:(mat==1)?bk:bv;

            f32x4 acc0 = {0.f,0.f,0.f,0.f};   // actual col 2c
            f32x4 acc1 = {0.f,0.f,0.f,0.f};   // actual col 2c+1
            const short* Wp0 = WF + (size_t)((h*2+0)*6) * 512 + lane * 8;
            const short* Wp1 = WF + (size_t)((h*2+1)*6) * 512 + lane * 8;
            #pragma unroll
            for (int kk = 0; kk < 6; kk++) {
                short8 b0 = *(const short8*)(Wp0 + kk * 512);
                short8 b1 = *(const short8*)(Wp1 + kk * 512);
                acc0 = MFMA16(a[kk], b0, acc0);
                acc1 = MFMA16(a[kk], b1, acc1);
            }
            float bv0 = 0.f, bv1 = 0.f;
            if (2*c < 24) {
                float2 bb = *(const float2*)(bias + h * 24 + 2 * c);
                bv0 = bb.x; bv1 = bb.y;
            }

            if (mat == 0) {
                #pragma unroll
                for (int r = 0; r < 4; r++) {
                    float v0 = (acc0[r] + bv0) * SCALE_Q;
                    float v1 = (c == 15) ? 1.0f : (acc1[r] + bv1) * SCALE_Q;
                    *(unsigned*)(Q + ((size_t)bh * SS + s0 + r) * DHP + 2*c) = pk2(v0, v1);
                }
            } else if (mat == 1) {
                #pragma unroll
                for (int r = 0; r < 4; r++) {
                    float v0 = acc0[r] + bv0;
                    float v1 = (c == 15) ? ((mrow[r] != 0.f) ? 0.f : -1e30f)
                                         : (acc1[r] + bv1);
                    *(unsigned*)(K + ((size_t)bh * SS + dst[r]) * DHP + 2*c) = pk2(v0, v1);
                }
            } else {
                #pragma unroll
                for (int r = 0; r < 4; r++) {
                    float v0 = (c == 12) ? 1.0f : (acc0[r] + bv0);  // col 24 = ones
                    float v1 = acc1[r] + bv1;
                    *(unsigned*)(Vc + ((size_t)bh * SS + dst[r]) * DHP + 2*c) = pk2(v0, v1);
                }
            }
        }
    }
}

// ---------------- vtrans: Vc[s_c][e] -> Vt[e][s_c] (LDS tile transpose) ----------------
__global__ __launch_bounds__(256) void vtrans_kernel(
    const short* __restrict__ Vc, short* __restrict__ Vt)
{
    __shared__ short tile[256][33];
    int bh = blockIdx.x, c4 = blockIdx.y;
    int t = threadIdx.x;
    const short* src = Vc + ((size_t)bh * SS + c4 * 256 + t) * DHP;
    short8 a0 = *(const short8*)(src);
    short8 a1 = *(const short8*)(src + 8);
    short8 a2 = *(const short8*)(src + 16);
    short8 a3 = *(const short8*)(src + 24);
    #pragma unroll
    for (int i = 0; i < 8; i++) {
        tile[t][i]      = a0[i];
        tile[t][8 + i]  = a1[i];
        tile[t][16 + i] = a2[i];
        tile[t][24 + i] = a3[i];
    }
    __syncthreads();
    int e = t & 31, jg = t >> 5;
    if (e < 25) {   // Vt rows 25..31 never read by flash (acc cols unused)
        short* dstp = Vt + ((size_t)bh * DHP + e) * SS + c4 * 256 + jg * 32;
        short8 o[4];
        #pragma unroll
        for (int i = 0; i < 32; i++) o[i >> 3][i & 7] = tile[jg * 32 + i][e];
        #pragma unroll
        for (int i = 0; i < 4; i++) *(short8*)(dstp + i * 8) = o[i];
    }
}

// ---------------- flash attention (swapped QK^T, in-register softmax) ----------------
__device__ __forceinline__ void fproc(const f32x16& S, f32x16& acc,
                                      short8 v0, short8 v1)
{
    float p[16];
    #pragma unroll
    for (int r = 0; r < 16; r++) p[r] = __builtin_amdgcn_exp2f(S[r]);

    unsigned c01 = pk2(p[0],  p[1]);
    unsigned c23 = pk2(p[2],  p[3]);
    unsigned c45 = pk2(p[4],  p[5]);
    unsigned c67 = pk2(p[6],  p[7]);
    unsigned c89 = pk2(p[8],  p[9]);
    unsigned cab = pk2(p[10], p[11]);
    unsigned ccd = pk2(p[12], p[13]);
    unsigned cef = pk2(p[14], p[15]);

    // permlane32_swap(a,b): x[l] = l<32 ? a[l] : b[l-32]
    //                       y[l] = l<32 ? a[l+32] : b[l]
    uint2v s0 = __builtin_amdgcn_permlane32_swap(c01, c45, false, false);
    uint2v s1 = __builtin_amdgcn_permlane32_swap(c23, c67, false, false);
    uint2v s2 = __builtin_amdgcn_permlane32_swap(c89, ccd, false, false);
    uint2v s3 = __builtin_amdgcn_permlane32_swap(cab, cef, false, false);

    uint4v w0v = { s0.x, s1.x, s0.y, s1.y };   // PV A-frag, kpos tile 0..15
    uint4v w1v = { s2.x, s3.x, s2.y, s3.y };   // kpos tile 16..31
    short8 pa0 = __builtin_bit_cast(short8, w0v);
    short8 pa1 = __builtin_bit_cast(short8, w1v);

    acc = MFMA32(pa0, v0, acc);
    acc = MFMA32(pa1, v1, acc);
}

__global__ __launch_bounds__(256) void flash_kernel(
    const short* __restrict__ Q, const short* __restrict__ K, const short* __restrict__ Vt,
    const int* __restrict__ cnt, short* __restrict__ Af)
{
    __shared__ float llds[4][2][32];

    int idx = blockIdx.x;
    int bh = idx & 255;
    int qb = idx >> 8;          // 0..3
    int b = bh >> 3, h = bh & 7;

    int tid = threadIdx.x;
    int lane = tid & 63, w = tid >> 6;
    int l31 = lane & 31;
    int hi = lane >> 5;

    int nt = (cnt[b] + 31) >> 5;   // only tiles containing unmasked positions

    int qrA = qb * 256 + w * 32;
    int qrB = qrA + 128;

    const short* QpA = Q + ((size_t)bh * SS + qrA + l31) * DHP + hi * 8;
    const short* QpB = Q + ((size_t)bh * SS + qrB + l31) * DHP + hi * 8;
    short8 qA0 = *(const short8*)QpA;
    short8 qA1 = *(const short8*)(QpA + 16);
    short8 qB0 = *(const short8*)QpB;
    short8 qB1 = *(const short8*)(QpB + 16);

    const short* Kp = K + ((size_t)bh * SS + l31) * DHP + hi * 8;
    const short* Vp = Vt + ((size_t)bh * DHP + l31) * SS + hi * 8;

    f32x16 accA, accB, Z16;
    #pragma unroll
    for (int r = 0; r < 16; r++) { accA[r] = 0.f; accB[r] = 0.f; Z16[r] = 0.f; }

    for (int kt = 0; kt < nt; kt++) {
        short8 k0 = *(const short8*)(Kp);
        short8 k1 = *(const short8*)(Kp + 16);
        short8 v0 = *(const short8*)(Vp);
        short8 v1 = *(const short8*)(Vp + 16);
        Kp += 32 * DHP;
        Vp += 32;

        f32x16 SA = MFMA32(k0, qA0, Z16);
        SA = MFMA32(k1, qA1, SA);   // includes mask bias via channel e=31
        f32x16 SB = MFMA32(k0, qB0, Z16);
        SB = MFMA32(k1, qB1, SB);

        fproc(SA, accA, v0, v1);
        fproc(SB, accB, v0, v1);
    }

    // denominator via V's ones-column: acc col 24 (lanes l31==24)
    if (l31 == 24) {
        #pragma unroll
        for (int r = 0; r < 16; r++) {
            int row = (r & 3) + 8 * (r >> 2) + 4 * hi;
            llds[w][0][row] = __builtin_amdgcn_rcpf(accA[r]);
            llds[w][1][row] = __builtin_amdgcn_rcpf(accB[r]);
        }
    }
    __builtin_amdgcn_wave_barrier();   // same-wave LDS ordering fence

    // store O into fragment-order Af[(grow>>4)*24 + kk*4+g][c=row&15][8]
    if (l31 < 24) {
        int d = h * 24 + l31;
        int grpA = (b * SS + qrA) >> 4;
        int grpB = (b * SS + qrB) >> 4;
        size_t fcol = (size_t)((d >> 5) * 4 + ((d >> 3) & 3)) * 128 + (d & 7);
        short* opA = Af + (size_t)grpA * 3072 + fcol;   // 3072 = 24*128
        short* opB = Af + (size_t)grpB * 3072 + fcol;
        #pragma unroll
        for (int r = 0; r < 16; r++) {
            int row = (r & 3) + 8 * (r >> 2) + 4 * hi;
            size_t off = (size_t)(r >> 3) * 3072 + (size_t)(row & 15) * 8;
            opA[off] = nb(accA[r] * llds[w][0][row]);
            opB[off] = nb(accB[r] * llds[w][1][row]);
        }
    }
}

// ---------------- final: out = attn(bf16) @ Wo + bo (Wo split hi+lo) ----------------
__global__ __launch_bounds__(256) void final_kernel(
    const short* __restrict__ Af,
    const short* __restrict__ WoFh, const short* __restrict__ WoFl,
    const float* __restrict__ bo, float* __restrict__ out)
{
    int tid = threadIdx.x;
    int lane = tid & 63, w = tid >> 6;
    int c = lane & 15, g = lane >> 4;
    int r0 = blockIdx.x * 64 + w * 16;
    int n0 = blockIdx.y * 6;

    short8 a[6];
    #pragma unroll
    for (int kk = 0; kk < 6; kk++)
        a[kk] = *(const short8*)(Af + ((size_t)(r0 >> 4) * 24 + kk*4 + g) * 128 + c * 8);

    f32x4 acc[6];
    #pragma unroll
    for (int n = 0; n < 6; n++) acc[n] = (f32x4){0.f,0.f,0.f,0.f};

    #pragma unroll
    for (int kk = 0; kk < 6; kk++) {
        #pragma unroll
        for (int n = 0; n < 6; n++) {
            const short* bh_p = WoFh + (size_t)((n0+n)*6 + kk) * 512 + lane * 8;
            const short* bl_p = WoFl + (size_t)((n0+n)*6 + kk) * 512 + lane * 8;
            short8 bh = *(const short8*)bh_p;
            short8 bl = *(const short8*)bl_p;
            acc[n] = MFMA16(a[kk], bh, acc[n]);
            acc[n] = MFMA16(a[kk], bl, acc[n]);
        }
    }

    #pragma unroll
    for (int n = 0; n < 6; n++) {
        int col = (n0+n)*16 + c;
        float bv = bo[col];
        #pragma unroll
        for (int r = 0; r < 4; r++) {
            out[(size_t)(r0 + g*4 + r) * DD + col] = acc[n][r] + bv;
        }
    }
}

extern "C" void kernel_launch(void* const* d_in, const int* in_sizes, int n_in,
                              void* d_out, int out_size, void* d_ws, size_t ws_size,
                              hipStream_t stream)
{
    const float* x    = (const float*)d_in[0];
    const void*  mask = d_in[1];
    const float* Wq   = (const float*)d_in[2];
    const float* bq   = (const float*)d_in[3];
    const float* Wk   = (const float*)d_in[4];
    const float* bk   = (const float*)d_in[5];
    const float* Wv   = (const float*)d_in[6];
    const float* bv   = (const float*)d_in[7];
    const float* Wo   = (const float*)d_in[8];
    const float* bo   = (const float*)d_in[9];
    float* out = (float*)d_out;

    char* ws = (char*)d_ws;
    size_t off = 0;
    float* maskf = (float*)(ws + off); off += (size_t)BB*SS*4;          // 128 KB
    short* Q     = (short*)(ws + off); off += (size_t)BB*HH*SS*DHP*2;   // 16 MB
    short* K     = (short*)(ws + off); off += (size_t)BB*HH*SS*DHP*2;   // 16 MB
    short* Vt    = (short*)(ws + off); off += (size_t)BB*HH*SS*DHP*2;   // 16 MB
    short* Af    = (short*)(ws + off); off += (size_t)BB*SS*DD*2;       // 12 MB
    short* WqF   = (short*)(ws + off); off += (size_t)HH*DHP*DD*2;
    short* WkF   = (short*)(ws + off); off += (size_t)HH*DHP*DD*2;
    short* WvF   = (short*)(ws + off); off += (size_t)HH*DHP*DD*2;
    short* WoFh  = (short*)(ws + off); off += (size_t)DD*DD*2;
    short* WoFl  = (short*)(ws + off); off += (size_t)DD*DD*2;
    short* Vc    = (short*)(ws + off); off += (size_t)BB*HH*SS*DHP*2;   // 16 MB
    int*   inv   = (int*)  (ws + off); off += (size_t)BB*SS*4;          // 128 KB
    int*   cnt   = (int*)  (ws + off); off += 256;

    prep_kernel<<<dim3(848), dim3(256), 0, stream>>>(
        mask, Wq, Wk, Wv, Wo, maskf, WqF, WkF, WvF, WoFh, WoFl);
    scan_kernel<<<dim3(BB), dim3(1024), 0, stream>>>(maskf, inv, cnt);
    proj_kernel<<<dim3(512, 4), dim3(256), 0, stream>>>(
        x, bq, bk, bv, WqF, WkF, WvF, maskf, inv, Q, K, Vc);
    vtrans_kernel<<<dim3(256, 4), dim3(256), 0, stream>>>(Vc, Vt);
    flash_kernel<<<dim3(1024), dim3(256), 0, stream>>>(
        Q, K, Vt, cnt, Af);
    final_kernel<<<dim3(512, 2), dim3(256), 0, stream>>>(
        Af, WoFh, WoFl, bo, out);
}